// Round 1
// baseline (725.610 us; speedup 1.0000x reference)
//
#include <hip/hip_runtime.h>

#define NSTEPS 512
#define BATCH  65536

// Heston constants (float32, matching reference)
#define C_DT       (1.0f / 512.0f)
#define C_SQRT_DT  0.04419417382415922f      // sqrt(1/512)
#define C_RHO      (-0.7f)
#define C_RHOPERP  0.7141428428542850f       // sqrt(1 - 0.49)
#define C_V0       0.055225f                 // 0.235^2
#define C_THETA    0.04f
#define C_SIGMAV   2.0f
#define C_S0       100.0f
// KAPPA == 1.0 (folded into the drift term)

__global__ __launch_bounds__(256) void heston_paths(
    const float* __restrict__ Zvol,   // [BATCH, NSTEPS, 2]
    const float* __restrict__ Zp,     // [BATCH, NSTEPS]
    float* __restrict__ S,            // [BATCH, NSTEPS+1]
    float* __restrict__ V)            // [BATCH, NSTEPS+1]
{
    const int b = blockIdx.x * blockDim.x + threadIdx.x;

    // Per-path row bases. Z_vol row = b*4096 B (16B aligned); Z_price row =
    // b*2048 B (16B aligned) -> float4 loads are naturally aligned.
    const float4* __restrict__ zv4 = (const float4*)(Zvol + (size_t)b * (NSTEPS * 2));
    const float4* __restrict__ zp4 = (const float4*)(Zp   + (size_t)b * NSTEPS);
    float* __restrict__ Srow = S + (size_t)b * (NSTEPS + 1);
    float* __restrict__ Vrow = V + (size_t)b * (NSTEPS + 1);

    float v    = C_V0;
    float logS = 0.0f;

    Srow[0] = C_S0;
    Vrow[0] = C_V0;

    // 8 steps per iteration: 4x float4 from Zvol (each float4 = 2 steps of
    // (zv, z_discard)), 2x float4 from Zp. 6 loads issued before any use ->
    // ~96 B/lane outstanding for latency hiding at 1 wave/SIMD occupancy.
    for (int k = 0; k < NSTEPS; k += 8) {
        const int q = k >> 1;            // float4 index into zv4
        float4 a0 = zv4[q + 0];
        float4 a1 = zv4[q + 1];
        float4 a2 = zv4[q + 2];
        float4 a3 = zv4[q + 3];
        float4 p0 = zp4[(k >> 2) + 0];
        float4 p1 = zp4[(k >> 2) + 1];

        float zv[8] = {a0.x, a0.z, a1.x, a1.z, a2.x, a2.z, a3.x, a3.z};
        float zp[8] = {p0.x, p0.y, p0.z, p0.w, p1.x, p1.y, p1.z, p1.w};

        float sOut[8], vOut[8];
        #pragma unroll
        for (int j = 0; j < 8; ++j) {
            const float vpos  = fmaxf(v, 0.0f);
            // V_next = V + (THETA - Vpos)*dt + SIGMA_V*sqrt(Vpos*dt)*zv
            float vnext = v + (C_THETA - vpos) * C_DT
                            + C_SIGMAV * sqrtf(vpos * C_DT) * zv[j];
            vnext = fmaxf(vnext, 0.0f);
            // dB = rho*sqrt_dt*zv + rho_perp*sqrt_dt*zp
            const float dB = C_RHO * C_SQRT_DT * zv[j] + C_RHOPERP * C_SQRT_DT * zp[j];
            logS += -0.5f * vpos * C_DT + sqrtf(vpos) * dB;
            sOut[j] = C_S0 * __expf(logS);
            vOut[j] = vnext;
            v = vnext;
        }

        #pragma unroll
        for (int j = 0; j < 8; ++j) {
            Srow[k + 1 + j] = sOut[j];
            Vrow[k + 1 + j] = vOut[j];
        }
    }
}

extern "C" void kernel_launch(void* const* d_in, const int* in_sizes, int n_in,
                              void* d_out, int out_size, void* d_ws, size_t ws_size,
                              hipStream_t stream) {
    const float* Zvol = (const float*)d_in[0];   // [65536, 512, 2] f32
    const float* Zp   = (const float*)d_in[1];   // [65536, 512] f32
    float* S = (float*)d_out;                                  // [65536, 513]
    float* V = S + (size_t)BATCH * (NSTEPS + 1);               // [65536, 513]

    heston_paths<<<BATCH / 256, 256, 0, stream>>>(Zvol, Zp, S, V);
}

// Round 2
// 624.300 us; speedup vs baseline: 1.1623x; 1.1623x over previous
//
#include <hip/hip_runtime.h>

#define NSTEPS 512
#define BATCH  65536
#define NOUT   (NSTEPS + 1)      // 513
#define TILE   64                // steps per LDS tile
#define PAD    65                // 64+1: bank-conflict-free both phases

// Heston constants (float32, matching reference)
#define C_DT       (1.0f / 512.0f)
#define C_SQRT_DT  0.04419417382415922f      // sqrt(1/512)
#define C_RHO      (-0.7f)
#define C_RHOPERP  0.7141428428542850f       // sqrt(1 - 0.49)
#define C_V0       0.055225f                 // 0.235^2
#define C_THETA    0.04f
#define C_SIGMAV   2.0f
#define C_S0       100.0f
// KAPPA == 1.0 (folded into the drift term)

// One wave per block; each lane owns one path. Outputs staged through LDS
// and written transposed: lane i writes col (k0+i) of each of the wave's 64
// rows -> 256 B contiguous per store instruction -> no partial-line RMW.
__global__ __launch_bounds__(64) void heston_paths(
    const float* __restrict__ Zvol,   // [BATCH, NSTEPS, 2]
    const float* __restrict__ Zp,     // [BATCH, NSTEPS]
    float* __restrict__ S,            // [BATCH, NOUT]
    float* __restrict__ V)            // [BATCH, NOUT]
{
    __shared__ float St[64][PAD];
    __shared__ float Vt[64][PAD];

    const int lane     = threadIdx.x;          // 0..63
    const int pathBase = blockIdx.x * 64;
    const int b        = pathBase + lane;

    const float4* __restrict__ zv4 = (const float4*)(Zvol + (size_t)b * (NSTEPS * 2));
    const float4* __restrict__ zp4 = (const float4*)(Zp   + (size_t)b * NSTEPS);

    float v    = C_V0;
    float logS = 0.0f;

    // Column 0 (t=0). These 64B-partial lines get completed by tile-0's
    // coalesced writes moments later within the same wave -> L2 combines.
    S[(size_t)b * NOUT] = C_S0;
    V[(size_t)b * NOUT] = C_V0;

    for (int k0 = 0; k0 < NSTEPS; k0 += TILE) {
        // ---- compute phase: 64 steps, 8 per chunk, results into LDS ----
        #pragma unroll
        for (int kk = 0; kk < TILE; kk += 8) {
            const int k = k0 + kk;
            const int q = k >> 1;                 // float4 index into zv4
            float4 a0 = zv4[q + 0];
            float4 a1 = zv4[q + 1];
            float4 a2 = zv4[q + 2];
            float4 a3 = zv4[q + 3];
            float4 p0 = zp4[(k >> 2) + 0];
            float4 p1 = zp4[(k >> 2) + 1];

            float zv[8] = {a0.x, a0.z, a1.x, a1.z, a2.x, a2.z, a3.x, a3.z};
            float zp[8] = {p0.x, p0.y, p0.z, p0.w, p1.x, p1.y, p1.z, p1.w};

            #pragma unroll
            for (int j = 0; j < 8; ++j) {
                const float vpos  = fmaxf(v, 0.0f);
                float vnext = v + (C_THETA - vpos) * C_DT
                                + C_SIGMAV * sqrtf(vpos * C_DT) * zv[j];
                vnext = fmaxf(vnext, 0.0f);
                const float dB = C_RHO * C_SQRT_DT * zv[j]
                               + C_RHOPERP * C_SQRT_DT * zp[j];
                logS += -0.5f * vpos * C_DT + sqrtf(vpos) * dB;
                St[lane][kk + j] = C_S0 * __expf(logS);   // banks (lane+c)%32: free
                Vt[lane][kk + j] = vnext;
                v = vnext;
            }
        }

        // Single-wave block: DS ops are in-order per wave; we only need the
        // writes retired (lgkmcnt 0) + a compiler reorder fence. Avoids
        // s_barrier's full vmcnt(0) drain so next-tile loads stay in flight.
        asm volatile("s_waitcnt lgkmcnt(0)" ::: "memory");
        __builtin_amdgcn_wave_barrier();

        // ---- write-out phase: transposed, coalesced 256 B per store ----
        const size_t outBase = (size_t)pathBase * NOUT + 1 + k0 + lane;
        #pragma unroll 8
        for (int r = 0; r < 64; ++r) {
            S[outBase + (size_t)r * NOUT] = St[r][lane];  // banks (r+lane)%32: free
            V[outBase + (size_t)r * NOUT] = Vt[r][lane];
        }

        asm volatile("s_waitcnt lgkmcnt(0)" ::: "memory");
        __builtin_amdgcn_wave_barrier();
    }
}

extern "C" void kernel_launch(void* const* d_in, const int* in_sizes, int n_in,
                              void* d_out, int out_size, void* d_ws, size_t ws_size,
                              hipStream_t stream) {
    const float* Zvol = (const float*)d_in[0];   // [65536, 512, 2] f32
    const float* Zp   = (const float*)d_in[1];   // [65536, 512] f32
    float* S = (float*)d_out;                                  // [65536, 513]
    float* V = S + (size_t)BATCH * NOUT;                       // [65536, 513]

    heston_paths<<<BATCH / 64, 64, 0, stream>>>(Zvol, Zp, S, V);
}